// Round 11
// baseline (1779.008 us; speedup 1.0000x reference)
//
#include <hip/hip_runtime.h>

// TranslationInvariantMP, 4-pass (MI355X/gfx950), original dataflow:
//   P1: a0 = aggTI(x)        (gather, raw agg -> ws compact [VN][64])
//   P2: h0 = elu(a0 @ W0)    (register-tiled GEMM + ELU epilogue)
//   P3: a1 = agg(h0)         (gather on out[:,0:64], stride 512B)
//   P4: h1 = elu(a1 @ W1+b1) (GEMM + bias + ELU)
// Round-9 lesson: wave-uniform row loads in the matvec serialize on the
// scalar path (121-201 us). GEMM now tiles 64x64 per block with A^T in LDS:
// k-loop = 2 x ds_read_b128 -> 16 FMA per thread, all lanes load distinct data.

constexpr int VN  = 100000;
constexpr int KN  = 32;
constexpr int FN  = 64;
constexpr int WPB = 4;               // waves per block
constexpr int TPW = 8;               // vertices per wave (gather)
constexpr int VPB = WPB * TPW;       // 32 vertices/block -> 3125 blocks exact

__device__ float g_scratch[(size_t)VN * FN];   // fallback if ws too small

// ---------------- gather: raw weighted aggregation -> ws ----------------
template <bool FIRST, int RBYTES>
__global__ __launch_bounds__(256, 4)
void gather_raw(const float* __restrict__ src,    // rows RBYTES apart (cols 0:64)
                const int*   __restrict__ nbidx,  // [VN][32]
                const float* __restrict__ distsq, // [VN][32]
                float*       __restrict__ dst)    // [VN][64] compact
{
    const int lane = threadIdx.x & 63;
    const int wid  = threadIdx.x >> 6;
    const int tq   = lane >> 4;
    const int fq   = lane & 15;

    __shared__ float s_wo[WPB][TPW * 68];

    const int vbase = (blockIdx.x * WPB + wid) * TPW;

    {   // stage (w_k, byte-offset_k) for this wave's 8 vertices
        float4 d4 = ((const float4*)(distsq + (size_t)vbase * KN))[lane];
        int4   i4 = ((const int4*)  (nbidx  + (size_t)vbase * KN))[lane];
        const int s = 4 * lane;
        float* dstp = s_wo[wid] + (s >> 5) * 68 + (s & 31) * 2;
        float4 lo, hi;
        lo.x = __expf(-10.0f * d4.x); lo.y = __int_as_float(i4.x * RBYTES);
        lo.z = __expf(-10.0f * d4.y); lo.w = __int_as_float(i4.y * RBYTES);
        hi.x = __expf(-10.0f * d4.z); hi.y = __int_as_float(i4.z * RBYTES);
        hi.z = __expf(-10.0f * d4.w); hi.w = __int_as_float(i4.w * RBYTES);
        ((float4*)dstp)[0] = lo;
        ((float4*)dstp)[1] = hi;
        // same-wave DS in-order; per-wid slice -> no barrier needed
    }

    const float invK = 1.0f / KN;
    const char* sb = (const char*)src + (size_t)fq * 16;

#pragma unroll
    for (int g = 0; g < 2; ++g) {
        const int vl = g * 4 + tq;
        const int vt = vbase + vl;
        const float* wo = s_wo[wid] + vl * 68;

        float4 a0 = {0, 0, 0, 0}, a1 = {0, 0, 0, 0};
        float  ws0 = 0.0f, ws1 = 0.0f;
#pragma unroll
        for (int k = 0; k < KN; k += 2) {
            float4 p = *(const float4*)(wo + 2 * k);  // {w,o,w,o}
            float4 x0 = *(const float4*)(sb + __float_as_int(p.y));
            float4 x1 = *(const float4*)(sb + __float_as_int(p.w));
            a0.x += p.x * x0.x; a0.y += p.x * x0.y;
            a0.z += p.x * x0.z; a0.w += p.x * x0.w;
            a1.x += p.z * x1.x; a1.y += p.z * x1.y;
            a1.z += p.z * x1.z; a1.w += p.z * x1.w;
            if (FIRST) { ws0 += p.x; ws1 += p.z; }
        }
        float4 acc;
        acc.x = a0.x + a1.x; acc.y = a0.y + a1.y;
        acc.z = a0.z + a1.z; acc.w = a0.w + a1.w;

        if (FIRST) {
            const float wsum = ws0 + ws1;
            float4 self = *(const float4*)(sb + (size_t)vt * RBYTES);
            acc.x -= self.x * wsum; acc.y -= self.y * wsum;
            acc.z -= self.z * wsum; acc.w -= self.w * wsum;
        }
        acc.x *= invK; acc.y *= invK; acc.z *= invK; acc.w *= invK;

        *(float4*)(dst + (size_t)vt * FN + fq * 4) = acc;
    }
}

// --------- GEMM: C[v][j] = elu( sum_k A[v][k]*W[k][j] (+ b[j]) ) ---------
// A: ws compact [VN][64]. C: out[v][128] at column offset OUTCOL.
constexpr int GT_V = 64;                        // rows per block tile

template <bool BIAS, int OUTCOL>
__global__ __launch_bounds__(256, 4)
void gemm64(const float* __restrict__ A,        // [VN][64] compact
            const float* __restrict__ W,        // [64][64] row-major
            const float* __restrict__ bias,     // [64] or nullptr
            float*       __restrict__ out)      // [VN][128]
{
    const int tid  = threadIdx.x;
    const int wid  = tid >> 6;
    const int lane = tid & 63;
    const int vq   = lane >> 4;          // 4-row group within wave
    const int cq   = lane & 15;          // 4-col group

    __shared__ float s_at[GT_V][68];     // A^T: s_at[k][v]
    __shared__ float s_w [GT_V][68];     // W:   s_w[k][j]

    const int vbase = blockIdx.x * GT_V;
    const int rem   = VN - vbase;        // >=1; last block has 32

    // stage W (64x64 f32, coalesced float4, 2-way-free LDS writes)
#pragma unroll
    for (int i = 0; i < 4; ++i) {
        const int idx = i * 256 + tid;               // float4 index
        const int k   = idx >> 4;
        const int c   = (idx & 15) * 4;
        float4 wv = *(const float4*)(W + idx * 4);
        *(float4*)&s_w[k][c] = wv;
    }
    // stage A^T (guarded; scatter 4 x b32 per float4)
#pragma unroll
    for (int i = 0; i < 4; ++i) {
        const int idx = i * 256 + tid;
        const int v   = idx >> 4;
        const int k4  = (idx & 15) * 4;
        float4 av = {0, 0, 0, 0};
        if (v < rem) av = *(const float4*)(A + (size_t)(vbase + v) * FN + k4);
        s_at[k4 + 0][v] = av.x;
        s_at[k4 + 1][v] = av.y;
        s_at[k4 + 2][v] = av.z;
        s_at[k4 + 3][v] = av.w;
    }
    __syncthreads();

    // 4x4 register tile per thread: rows r0..r0+3, cols 4*cq..4*cq+3
    const int r0 = wid * 16 + vq * 4;
    float acc[4][4] = {};
#pragma unroll
    for (int k = 0; k < GT_V; ++k) {
        float4 av = *(const float4*)&s_at[k][r0];    // 4 rows (broadcast x16)
        float4 wv = *(const float4*)&s_w[k][4 * cq]; // 4 cols
        acc[0][0] += av.x * wv.x; acc[0][1] += av.x * wv.y;
        acc[0][2] += av.x * wv.z; acc[0][3] += av.x * wv.w;
        acc[1][0] += av.y * wv.x; acc[1][1] += av.y * wv.y;
        acc[1][2] += av.y * wv.z; acc[1][3] += av.y * wv.w;
        acc[2][0] += av.z * wv.x; acc[2][1] += av.z * wv.y;
        acc[2][2] += av.z * wv.z; acc[2][3] += av.z * wv.w;
        acc[3][0] += av.w * wv.x; acc[3][1] += av.w * wv.y;
        acc[3][2] += av.w * wv.z; acc[3][3] += av.w * wv.w;
    }

    float4 b4 = {0, 0, 0, 0};
    if (BIAS) b4 = *(const float4*)(bias + 4 * cq);

#pragma unroll
    for (int i = 0; i < 4; ++i) {
        const int v = r0 + i;
        if (v < rem) {
            float4 h;
            h.x = acc[i][0] + b4.x; h.y = acc[i][1] + b4.y;
            h.z = acc[i][2] + b4.z; h.w = acc[i][3] + b4.w;
            h.x = (h.x > 0.0f) ? h.x : __expf(h.x) - 1.0f;
            h.y = (h.y > 0.0f) ? h.y : __expf(h.y) - 1.0f;
            h.z = (h.z > 0.0f) ? h.z : __expf(h.z) - 1.0f;
            h.w = (h.w > 0.0f) ? h.w : __expf(h.w) - 1.0f;
            *(float4*)(out + (size_t)(vbase + v) * 128 + OUTCOL + 4 * cq) = h;
        }
    }
}

extern "C" void kernel_launch(void* const* d_in, const int* in_sizes, int n_in,
                              void* d_out, int out_size, void* d_ws, size_t ws_size,
                              hipStream_t stream) {
    const float* x   = (const float*)d_in[0];
    const int*   nb  = (const int*)  d_in[1];
    const float* dsq = (const float*)d_in[2];
    const float* W0  = (const float*)d_in[3];
    const float* W1  = (const float*)d_in[4];
    const float* b1  = (const float*)d_in[5];
    float* out = (float*)d_out;

    const size_t need = (size_t)VN * FN * sizeof(float);
    float* ws = (ws_size >= need) ? (float*)d_ws : g_scratch;

    const int gblocks = VN / VPB;                    // 3125 exact
    const int mblocks = (VN + GT_V - 1) / GT_V;      // 1563

    // P1: a0 = aggTI(x) -> ws           (x rows 256B)
    gather_raw<true, 256><<<gblocks, 256, 0, stream>>>(x, nb, dsq, ws);
    // P2: h0 = elu(a0 @ W0) -> out[:,0:64]
    gemm64<false, 0><<<mblocks, 256, 0, stream>>>(ws, W0, nullptr, out);
    // P3: a1 = agg(h0) -> ws            (h0 rows at out, stride 512B)
    gather_raw<false, 512><<<gblocks, 256, 0, stream>>>(out, nb, dsq, ws);
    // P4: h1 = elu(a1 @ W1 + b1) -> out[:,64:128]
    gemm64<true, 64><<<mblocks, 256, 0, stream>>>(ws, W1, b1, out);
}

// Round 15
// 244.853 us; speedup vs baseline: 7.2656x; 7.2656x over previous
//
#include <hip/hip_runtime.h>
#include <hip/hip_fp16.h>

// TranslationInvariantMP, 5-pass with fp16 gather payload (MI355X/gfx950):
//   C0: x_h  = fp16(x)                    (stream convert, 38 MB)
//   P1: a0   = aggTI(x_h)      -> ws fp32 (random gather, 128B rows = 1 line)
//   P2: h0   = elu(a0 @ W0)    -> out[:,0:64] fp32  AND h_h fp16 mirror
//   P3: a1   = agg(h_h)        -> ws fp32
//   P4: h1   = elu(a1 @ W1+b1) -> out[:,64:128]
// Round-11 lessons: tiled gemm64 had spill-shaped traffic (2.3 GB, VALU 1.2%)
// -> revert to the round-2 LDS-broadcast matvec (measured 45 us). Gather is
// line-rate-limited (~4 TB/s fill at fp32) -> halve lines with fp16 payload.

constexpr int VN  = 100000;
constexpr int KN  = 32;
constexpr int FN  = 64;
constexpr int WPB = 4;
constexpr int TPW = 8;
constexpr int VPB = WPB * TPW;       // 32 -> 3125 blocks exact

// fallback scratch: 25.6 MB fp32 + 2 x 12.8 MB fp16 = 51.2 MB
__device__ unsigned char g_scratch[(size_t)VN * FN * 8];

union HU { unsigned u; __half2 h; };

// ---------------- C0: fp32 -> fp16 stream convert ----------------
__global__ __launch_bounds__(256)
void f2h(const float* __restrict__ in, __half* __restrict__ oh, int n4)
{
    const int i = blockIdx.x * 256 + threadIdx.x;   // one float4 per thread
    if (i >= n4) return;
    float4 v = ((const float4*)in)[i];
    HU lo, hi;
    lo.h = __floats2half2_rn(v.x, v.y);
    hi.h = __floats2half2_rn(v.z, v.w);
    uint2 o; o.x = lo.u; o.y = hi.u;
    ((uint2*)oh)[i] = o;
}

// ---------------- gather: fp16 source, fp32 accumulate ----------------
template <bool FIRST>
__global__ __launch_bounds__(256, 4)
void gather_h(const __half* __restrict__ src,    // [VN][64] fp16, 128B rows
              const int*    __restrict__ nbidx,  // [VN][32] int32
              const float*  __restrict__ distsq, // [VN][32] f32
              float*        __restrict__ dst)    // [VN][64] fp32 compact
{
    const int lane = threadIdx.x & 63;
    const int wid  = threadIdx.x >> 6;
    const int tq   = lane >> 4;        // vertex within quad
    const int fq   = lane & 15;        // 4-feature slice

    __shared__ float s_wo[WPB][TPW * 68];

    const int vbase = (blockIdx.x * WPB + wid) * TPW;

    {   // stage (w_k, byte-offset_k); fp16 rows are 128B apart
        float4 d4 = ((const float4*)(distsq + (size_t)vbase * KN))[lane];
        int4   i4 = ((const int4*)  (nbidx  + (size_t)vbase * KN))[lane];
        const int s = 4 * lane;
        float* dstp = s_wo[wid] + (s >> 5) * 68 + (s & 31) * 2;
        float4 lo, hi;
        lo.x = __expf(-10.0f * d4.x); lo.y = __int_as_float(i4.x * 128);
        lo.z = __expf(-10.0f * d4.y); lo.w = __int_as_float(i4.y * 128);
        hi.x = __expf(-10.0f * d4.z); hi.y = __int_as_float(i4.z * 128);
        hi.z = __expf(-10.0f * d4.w); hi.w = __int_as_float(i4.w * 128);
        ((float4*)dstp)[0] = lo;
        ((float4*)dstp)[1] = hi;
        // same-wave DS in-order; per-wid slice -> no barrier needed
    }

    const float invK = 1.0f / KN;
    const char* sb = (const char*)src + (size_t)fq * 8;   // 8B = 4 halfs per lane

#pragma unroll
    for (int g = 0; g < 2; ++g) {
        const int vl = g * 4 + tq;
        const int vt = vbase + vl;
        const float* wo = s_wo[wid] + vl * 68;

        float4 a0 = {0, 0, 0, 0}, a1 = {0, 0, 0, 0};
        float  ws0 = 0.0f, ws1 = 0.0f;
#pragma unroll
        for (int k = 0; k < KN; k += 2) {
            float4 p  = *(const float4*)(wo + 2 * k);     // {w,o,w,o}
            uint2  r0 = *(const uint2*)(sb + __float_as_int(p.y));
            uint2  r1 = *(const uint2*)(sb + __float_as_int(p.w));
            HU u;  float2 f;
            u.u = r0.x; f = __half22float2(u.h);
            a0.x += p.x * f.x; a0.y += p.x * f.y;
            u.u = r0.y; f = __half22float2(u.h);
            a0.z += p.x * f.x; a0.w += p.x * f.y;
            u.u = r1.x; f = __half22float2(u.h);
            a1.x += p.z * f.x; a1.y += p.z * f.y;
            u.u = r1.y; f = __half22float2(u.h);
            a1.z += p.z * f.x; a1.w += p.z * f.y;
            if (FIRST) { ws0 += p.x; ws1 += p.z; }
        }
        float4 acc;
        acc.x = a0.x + a1.x; acc.y = a0.y + a1.y;
        acc.z = a0.z + a1.z; acc.w = a0.w + a1.w;

        if (FIRST) {   // translation invariance: acc -= x_v * sum_k w_k
            const float wsum = ws0 + ws1;
            uint2 sr = *(const uint2*)(sb + (size_t)vt * 128);
            HU u; float2 f;
            u.u = sr.x; f = __half22float2(u.h);
            acc.x -= f.x * wsum; acc.y -= f.y * wsum;
            u.u = sr.y; f = __half22float2(u.h);
            acc.z -= f.x * wsum; acc.w -= f.y * wsum;
        }
        acc.x *= invK; acc.y *= invK; acc.z *= invK; acc.w *= invK;

        *(float4*)(dst + (size_t)vt * FN + fq * 4) = acc;
    }
}

// ------- matvec (round-2 structure, measured 45us) + ELU epilogue -------
// h[v][j] = elu( sum_f A[v][f]*W[f][j] (+ b[j]) ); optional fp16 mirror.
template <bool BIAS, bool HOUT, int OUTCOL>
__global__ __launch_bounds__(256, 4)
void mv64(const float* __restrict__ A,      // [VN][64] fp32 compact
          const float* __restrict__ W,      // [64][64]
          const float* __restrict__ bias,   // [64] or nullptr
          float*       __restrict__ out,    // [VN][128]
          __half*      __restrict__ hdst)   // [VN][64] fp16 or nullptr
{
    const int lane = threadIdx.x & 63;
    const int wid  = threadIdx.x >> 6;
    const int tq   = lane >> 4;
    const int fq   = lane & 15;

    __shared__ float s_x[WPB][TPW * 68];

    float wreg[FN];                        // lane j holds W[:,j]
#pragma unroll
    for (int f = 0; f < FN; ++f) wreg[f] = W[f * FN + lane];
    const float hb = BIAS ? bias[lane] : 0.0f;

    const int vbase = (blockIdx.x * WPB + wid) * TPW;

#pragma unroll
    for (int i = 0; i < 2; ++i) {
        const int r = i * 4 + tq;
        float4 xv = *(const float4*)(A + (size_t)(vbase + r) * FN + fq * 4);
        *(float4*)(s_x[wid] + r * 68 + fq * 4) = xv;
    }
    // same-wave DS in-order; per-wave private slice -> no barrier

#pragma unroll
    for (int r = 0; r < TPW; ++r) {
        const float* xr = s_x[wid] + r * 68;
        float hacc[4] = {0, 0, 0, 0};
#pragma unroll
        for (int f4 = 0; f4 < 16; ++f4) {
            float4 a = *(const float4*)(xr + f4 * 4);   // uniform broadcast
            hacc[f4 & 3] += a.x * wreg[f4 * 4 + 0] + a.y * wreg[f4 * 4 + 1]
                          + a.z * wreg[f4 * 4 + 2] + a.w * wreg[f4 * 4 + 3];
        }
        float h = (hacc[0] + hacc[1]) + (hacc[2] + hacc[3]) + hb;
        h = (h > 0.0f) ? h : __expf(h) - 1.0f;
        out[(size_t)(vbase + r) * 128 + OUTCOL + lane] = h;
        if (HOUT) hdst[(size_t)(vbase + r) * FN + lane] = __float2half_rn(h);
    }
}

extern "C" void kernel_launch(void* const* d_in, const int* in_sizes, int n_in,
                              void* d_out, int out_size, void* d_ws, size_t ws_size,
                              hipStream_t stream) {
    const float* x   = (const float*)d_in[0];
    const int*   nb  = (const int*)  d_in[1];
    const float* dsq = (const float*)d_in[2];
    const float* W0  = (const float*)d_in[3];
    const float* W1  = (const float*)d_in[4];
    const float* b1  = (const float*)d_in[5];
    float* out = (float*)d_out;

    const size_t need = (size_t)VN * FN * 8;   // 25.6MB f32 + 2x 12.8MB f16
    unsigned char* base = (ws_size >= need) ? (unsigned char*)d_ws : g_scratch;
    float*  a_buf = (float*)base;
    __half* x_h   = (__half*)(base + (size_t)VN * FN * 4);
    __half* h_h   = x_h + (size_t)VN * FN;

    const int gblocks = VN / VPB;          // 3125 exact
    const int cblocks = (VN * FN / 4) / 256;  // 6250 exact

    // C0: x_h = fp16(x)
    f2h<<<cblocks, 256, 0, stream>>>(x, x_h, VN * FN / 4);
    // P1: a0 = aggTI(x_h) -> a_buf
    gather_h<true><<<gblocks, 256, 0, stream>>>(x_h, nb, dsq, a_buf);
    // P2: h0 = elu(a0 @ W0) -> out[:,0:64] + h_h
    mv64<false, true, 0><<<gblocks, 256, 0, stream>>>(a_buf, W0, nullptr, out, h_h);
    // P3: a1 = agg(h_h) -> a_buf
    gather_h<false><<<gblocks, 256, 0, stream>>>(h_h, nb, dsq, a_buf);
    // P4: h1 = elu(a1 @ W1 + b1) -> out[:,64:128]
    mv64<true, false, 64><<<gblocks, 256, 0, stream>>>(a_buf, W1, b1, out, nullptr);
}